// Round 7
// baseline (262.850 us; speedup 1.0000x reference)
//
#include <hip/hip_runtime.h>
#include <cmath>

// ---------------------------------------------------------------------------
// NeuralField: hashgrid encode (8 levels x 8 feats, smoothstep) + MLP
// 64 -> 256 -> 256 -> 256 -> 1 (ReLU x3, linear out), N = 262144 points.
// R7: occupancy attack. HW wave-slot quantum is power-of-2 (m69: steps at
// 64/128/256 regs): 152-reg waves (R5/R6) -> 2 waves/SIMD regardless of LDS.
// Redesign for <=128 regs/wave: each wave does its 64 features in TWO
// ft-halves (acc 2x4 tiles = 32 regs), packing each half's ReLU'd bf16
// output into registers (16/half) and writing both after the mid-layer
// barrier (solves the in-place read/write conflict). 40 KB LDS + <=128 regs
// -> 4 blocks/CU, 16 waves/CU (2x R6). af LDS reads double (acceptable:
// LDS pipe has headroom). Weight L2 traffic unchanged.
// Tripwire: FETCH/WRITE >> 5 MB means the 128-reg cap spilled.
// ---------------------------------------------------------------------------

#define N_LEVELS 8
#define TABLE_PAD 8192
#define TILE_M 64
#define ACT_STRIDE 256       // shorts per activation row
#define ENC_STRIDE 64        // shorts per encode row

typedef __attribute__((ext_vector_type(8))) short short8;
typedef __attribute__((ext_vector_type(4))) float float4v;

struct LevelParams {
  float scale[N_LEVELS];
  int   res[N_LEVELS];
  int   size[N_LEVELS];
};

__device__ __forceinline__ unsigned short f2bf(float f) {
  unsigned int u = __float_as_uint(f);
  u += 0x7fffu + ((u >> 16) & 1u);      // round to nearest even
  return (unsigned short)(u >> 16);
}
__device__ __forceinline__ float bf2f(unsigned short h) {
  return __uint_as_float(((unsigned int)h) << 16);
}
__device__ __forceinline__ unsigned int pack2bf(float a, float b) {
  // relu + cvt + pack two bf16 into one uint
  a = a > 0.f ? a : 0.f;
  b = b > 0.f ? b : 0.f;
  return (unsigned int)f2bf(a) | ((unsigned int)f2bf(b) << 16);
}

// Pack W (K x 256 row-major f32) -> bf16 [kb][n][ki]: one lane's 16 B A-frag
// (output-feature n, k-chunk) is contiguous; a wave's 16 n x 32 k tile is a
// coalesced 1 KB chunk. Wp layout: [W0p: 2*256*32][W1p+W2p: 8*256*32 each]
__global__ void pack_weights_kernel(const float* __restrict__ W0,
                                    const float* __restrict__ W1,
                                    const float* __restrict__ W2,
                                    unsigned short* __restrict__ Wp) {
  int tid = blockIdx.x * blockDim.x + threadIdx.x;
  const float* src;
  int base, e;
  if (tid < 16384)        { src = W0; base = 0;     e = tid;         }
  else if (tid < 81920)   { src = W1; base = 16384; e = tid - 16384; }
  else if (tid < 147456)  { src = W2; base = 81920; e = tid - 81920; }
  else return;
  int ki = e & 31;
  int n  = (e >> 5) & 255;
  int kb = e >> 13;
  Wp[base + e] = f2bf(src[(kb * 32 + ki) * 256 + n]);
}

__global__ __launch_bounds__(256, 4) void neural_field_kernel(
    const float* __restrict__ x,
    const float* __restrict__ table,
    const unsigned short* __restrict__ Wp,
    const float* __restrict__ W3,
    float* __restrict__ out,
    LevelParams P) {
  // XOR-swizzled layouts (16 B granular), data stored [point m][feature k]:
  //   enc (stride 64):  (m, k) -> m*64  + ((chunk ^ (m&7)) *8 + k&7)
  //   act (stride 256): (m, k) -> m*256 + ((chunk ^ (m&15))*8 + k&7)
  __shared__ unsigned short bufE[TILE_M * ENC_STRIDE];   // 8 KB
  __shared__ unsigned short bufA[TILE_M * ACT_STRIDE];   // 32 KB

  const int t  = threadIdx.x;
  const int g0 = blockIdx.x * TILE_M;

  // ---------------- Phase 1: hashgrid encode -> bufE (K=64) ----------------
  {
    int p  = t & 63;       // point within tile
    int lg = t >> 6;       // 0..3 -> handles levels 2lg, 2lg+1
    float2 xy = ((const float2*)x)[g0 + p];
    for (int li = 0; li < 2; ++li) {
      int l = lg * 2 + li;
      float scale = P.scale[l];
      int res = P.res[l], size = P.size[l];
      float posx = xy.x * scale + 0.5f;
      float posy = xy.y * scale + 0.5f;
      float pgx = floorf(posx), pgy = floorf(posy);
      float fx = posx - pgx, fy = posy - pgy;
      float wx = fx * fx * (3.0f - 2.0f * fx);
      float wy = fy * fy * (3.0f - 2.0f * fy);
      int px = (int)pgx, py = (int)pgy;
      float acc[8] = {0, 0, 0, 0, 0, 0, 0, 0};
      for (int dy = 0; dy < 2; ++dy) {
        float wyv = dy ? wy : 1.0f - wy;
        for (int dx = 0; dx < 2; ++dx) {
          float wgt = (dx ? wx : 1.0f - wx) * wyv;
          int idx = (px + dx) + (py + dy) * res;
          if (idx >= size) idx -= size;   // idx < 2*size always
          const float4* tp =
              (const float4*)(table + ((size_t)l * TABLE_PAD + idx) * 8);
          float4 t0 = tp[0], t1 = tp[1];
          acc[0] += wgt * t0.x; acc[1] += wgt * t0.y;
          acc[2] += wgt * t0.z; acc[3] += wgt * t0.w;
          acc[4] += wgt * t1.x; acc[5] += wgt * t1.y;
          acc[6] += wgt * t1.z; acc[7] += wgt * t1.w;
        }
      }
      union { unsigned short s[8]; short8 v; } u;
      for (int j = 0; j < 8; ++j) u.s[j] = f2bf(acc[j]);
      int pos = (l ^ (p & 7)) * 8;        // chunk l, swizzled (8 chunks)
      *(short8*)&bufE[p * ENC_STRIDE + pos] = u.v;
    }
  }

  const int lane  = t & 63;
  const int w     = t >> 6;       // 0..3
  const int l15   = lane & 15;
  const int quad  = lane >> 4;
  const int wbase = w * 64;       // this wave's 64 OUTPUT FEATURES

  // ------- MFMA layer (transposed): D = W^T[64 x K] @ X^T[K x 64] ----------
  // Two ft-halves of 32 features each; acc 2x4 tiles (32 regs). Each half's
  // output is ReLU'd + packed to bf16 in registers (uint2 per tile); both
  // halves are written to LDS only after the (optional) mid-layer barrier.
  auto run_layer = [&](const unsigned short* inb, int in_stride, int smask,
                       unsigned short* outb, const unsigned short* Wpl,
                       int KB, bool inplace) {
    uint2 packed[2][2][4];   // [half][ft][pt]

    for (int h = 0; h < 2; ++h) {
      float4v acc[2][4];   // [ft][pt]
      for (int ft = 0; ft < 2; ++ft)
        for (int pt = 0; pt < 4; ++pt)
          acc[ft][pt] = (float4v){0.f, 0.f, 0.f, 0.f};

      for (int kb = 0; kb < KB; ++kb) {
        short8 wf[2], af[4];
        for (int ft = 0; ft < 2; ++ft) {
          int n = wbase + h * 32 + ft * 16 + l15;
          wf[ft] = *(const short8*)&Wpl[(kb * 256 + n) * 32 + quad * 8];
        }
        int kchunk = kb * 4 + quad;
        for (int pt = 0; pt < 4; ++pt) {
          int m = pt * 16 + l15;
          int pos = (kchunk ^ (m & smask)) * 8;
          af[pt] = *(const short8*)&inb[m * in_stride + pos];
        }
        for (int ft = 0; ft < 2; ++ft)
          for (int pt = 0; pt < 4; ++pt)
            acc[ft][pt] = __builtin_amdgcn_mfma_f32_16x16x32_bf16(
                wf[ft], af[pt], acc[ft][pt], 0, 0, 0);
      }

      // Pack this half: ReLU + bf16 (2 uints per tile).
      for (int ft = 0; ft < 2; ++ft)
        for (int pt = 0; pt < 4; ++pt) {
          packed[h][ft][pt].x = pack2bf(acc[ft][pt][0], acc[ft][pt][1]);
          packed[h][ft][pt].y = pack2bf(acc[ft][pt][2], acc[ft][pt][3]);
        }
    }

    if (inplace) __syncthreads();   // all reads done before overwrite

    // Epilogue: 16 ds_write_b64, already in next layer's [m][k] layout.
    // D tile (h,ft,pt): lane holds rows n0..n0+3, n0 = wbase+h*32+ft*16+quad*4
    // of col m = pt*16+l15.
    for (int h = 0; h < 2; ++h)
      for (int ft = 0; ft < 2; ++ft) {
        int n0 = wbase + h * 32 + ft * 16 + quad * 4;
        int chunk = n0 >> 3, within = n0 & 7;     // within in {0,4}
        for (int pt = 0; pt < 4; ++pt) {
          int m = pt * 16 + l15;
          int pos = (chunk ^ (m & 15)) * 8 + within;
          *(uint2*)&outb[m * ACT_STRIDE + pos] = packed[h][ft][pt];
        }
      }
  };

  __syncthreads();
  run_layer(bufE, ENC_STRIDE, 7,  bufA, Wp,         2, false);  // layer 0
  __syncthreads();
  run_layer(bufA, ACT_STRIDE, 15, bufA, Wp + 16384, 8, true);   // layer 1
  __syncthreads();
  run_layer(bufA, ACT_STRIDE, 15, bufA, Wp + 81920, 8, true);   // layer 2
  __syncthreads();

  // ---------------- Final layer: out[p] = h2[p] . W3 -----------------------
  {
    int p = t >> 2;          // point within tile (0..63)
    int q = t & 3;           // quarter of K=256
    float s = 0.f;
    for (int c8 = 0; c8 < 8; ++c8) {
      int chunk = q * 8 + c8;
      int pos = (chunk ^ (p & 15)) * 8;
      short8 h = *(const short8*)&bufA[p * ACT_STRIDE + pos];
      float4 w0v = *(const float4*)(W3 + chunk * 8);
      float4 w1v = *(const float4*)(W3 + chunk * 8 + 4);
      s += bf2f((unsigned short)h[0]) * w0v.x;
      s += bf2f((unsigned short)h[1]) * w0v.y;
      s += bf2f((unsigned short)h[2]) * w0v.z;
      s += bf2f((unsigned short)h[3]) * w0v.w;
      s += bf2f((unsigned short)h[4]) * w1v.x;
      s += bf2f((unsigned short)h[5]) * w1v.y;
      s += bf2f((unsigned short)h[6]) * w1v.z;
      s += bf2f((unsigned short)h[7]) * w1v.w;
    }
    s += __shfl_xor(s, 1);
    s += __shfl_xor(s, 2);
    if (q == 0) out[g0 + p] = s;
  }
}

extern "C" void kernel_launch(void* const* d_in, const int* in_sizes, int n_in,
                              void* d_out, int out_size, void* d_ws,
                              size_t ws_size, hipStream_t stream) {
  const float* x     = (const float*)d_in[0];
  const float* table = (const float*)d_in[1];
  const float* W0    = (const float*)d_in[2];
  const float* W1    = (const float*)d_in[3];
  const float* W2    = (const float*)d_in[4];
  const float* W3    = (const float*)d_in[5];
  float* out = (float*)d_out;
  int N = in_sizes[0] / 2;

  unsigned short* Wp = (unsigned short*)d_ws;   // 147456 bf16 = 288 KB

  // Level params, double precision to match the Python reference exactly.
  LevelParams P;
  const double c = 1.2599210739135742;
  double m = 1.0;
  for (int l = 0; l < N_LEVELS; ++l) {
    double scale_d = 16.0 * m - 1.0;
    int res = (int)std::ceil(scale_d) + 1;
    long long sz = ((long long)res * res + 7) / 8 * 8;
    if (sz > (1LL << 19)) sz = 1LL << 19;
    P.scale[l] = (float)scale_d;
    P.res[l]   = res;
    P.size[l]  = (int)sz;
    m *= c;
  }

  hipLaunchKernelGGL(pack_weights_kernel, dim3(576), dim3(256), 0, stream,
                     W0, W1, W2, Wp);
  hipLaunchKernelGGL(neural_field_kernel, dim3(N / TILE_M), dim3(256), 0,
                     stream, x, table, Wp, W3, out, P);
}

// Round 8
// 191.397 us; speedup vs baseline: 1.3733x; 1.3733x over previous
//
#include <hip/hip_runtime.h>
#include <cmath>

// ---------------------------------------------------------------------------
// NeuralField: hashgrid encode (8 levels x 8 feats, smoothstep) + MLP
// 64 -> 256 -> 256 -> 256 -> 1 (ReLU x3, linear out), N = 262144 points.
// R8: shrink the WAVE TILE to fit 128 regs for real. 512-thread blocks,
// TILE_M=64, 8 waves each owning 32 features (acc 2x4 tiles = 32 regs,
// wf 8, af 16 -> ~85 live). R3/R4/R7 all proved the 64-feature wave tile
// (64 acc + frags ~150 live) spills under any <=170-reg cap. Ping-pong
// buffers (no in-place hazard -> no deferred-pack registers). Encode:
// 1 level/thread (512 = 8 lvl x 64 pts). LDS 72 KB -> 2 blocks/CU
// (144 KB), (512,4) -> 128-reg cap, 16 waves/CU = 2x R6 concurrency at
// identical MFMA work. Spill tripwire: FETCH/WRITE >> 5 MB.
// ---------------------------------------------------------------------------

#define N_LEVELS 8
#define TABLE_PAD 8192
#define TILE_M 64
#define ACT_STRIDE 256       // shorts per activation row
#define ENC_STRIDE 64        // shorts per encode row

typedef __attribute__((ext_vector_type(8))) short short8;
typedef __attribute__((ext_vector_type(4))) float float4v;

struct LevelParams {
  float scale[N_LEVELS];
  int   res[N_LEVELS];
  int   size[N_LEVELS];
};

__device__ __forceinline__ unsigned short f2bf(float f) {
  unsigned int u = __float_as_uint(f);
  u += 0x7fffu + ((u >> 16) & 1u);      // round to nearest even
  return (unsigned short)(u >> 16);
}
__device__ __forceinline__ float bf2f(unsigned short h) {
  return __uint_as_float(((unsigned int)h) << 16);
}
__device__ __forceinline__ unsigned int pack2bf(float a, float b) {
  a = a > 0.f ? a : 0.f;
  b = b > 0.f ? b : 0.f;
  return (unsigned int)f2bf(a) | ((unsigned int)f2bf(b) << 16);
}

// Pack W (K x 256 row-major f32) -> bf16 [kb][n][ki]: one lane's 16 B A-frag
// (output-feature n, k-chunk) is contiguous; a wave's 16 n x 32 k tile is a
// coalesced 1 KB chunk. Wp layout: [W0p: 2*256*32][W1p+W2p: 8*256*32 each]
__global__ void pack_weights_kernel(const float* __restrict__ W0,
                                    const float* __restrict__ W1,
                                    const float* __restrict__ W2,
                                    unsigned short* __restrict__ Wp) {
  int tid = blockIdx.x * blockDim.x + threadIdx.x;
  const float* src;
  int base, e;
  if (tid < 16384)        { src = W0; base = 0;     e = tid;         }
  else if (tid < 81920)   { src = W1; base = 16384; e = tid - 16384; }
  else if (tid < 147456)  { src = W2; base = 81920; e = tid - 81920; }
  else return;
  int ki = e & 31;
  int n  = (e >> 5) & 255;
  int kb = e >> 13;
  Wp[base + e] = f2bf(src[(kb * 32 + ki) * 256 + n]);
}

__global__ __launch_bounds__(512, 4) void neural_field_kernel(
    const float* __restrict__ x,
    const float* __restrict__ table,
    const unsigned short* __restrict__ Wp,
    const float* __restrict__ W3,
    float* __restrict__ out,
    LevelParams P) {
  // XOR-swizzled layouts (16 B granular), data stored [point m][feature k]:
  //   enc (stride 64):  (m, k) -> m*64  + ((chunk ^ (m&7)) *8 + k&7)
  //   act (stride 256): (m, k) -> m*256 + ((chunk ^ (m&15))*8 + k&7)
  __shared__ unsigned short bufE[TILE_M * ENC_STRIDE];   // 8 KB
  __shared__ unsigned short bufA[TILE_M * ACT_STRIDE];   // 32 KB
  __shared__ unsigned short bufB[TILE_M * ACT_STRIDE];   // 32 KB

  const int t  = threadIdx.x;
  const int g0 = blockIdx.x * TILE_M;

  // ------------- Phase 1: hashgrid encode, 1 level/thread -> bufE ----------
  {
    int p = t & 63;        // point within tile
    int l = t >> 6;        // level 0..7
    float2 xy = ((const float2*)x)[g0 + p];
    float scale = P.scale[l];
    int res = P.res[l], size = P.size[l];
    float posx = xy.x * scale + 0.5f;
    float posy = xy.y * scale + 0.5f;
    float pgx = floorf(posx), pgy = floorf(posy);
    float fx = posx - pgx, fy = posy - pgy;
    float wx = fx * fx * (3.0f - 2.0f * fx);
    float wy = fy * fy * (3.0f - 2.0f * fy);
    int px = (int)pgx, py = (int)pgy;
    float acc[8] = {0, 0, 0, 0, 0, 0, 0, 0};
    for (int dy = 0; dy < 2; ++dy) {
      float wyv = dy ? wy : 1.0f - wy;
      for (int dx = 0; dx < 2; ++dx) {
        float wgt = (dx ? wx : 1.0f - wx) * wyv;
        int idx = (px + dx) + (py + dy) * res;
        if (idx >= size) idx -= size;   // idx < 2*size always
        const float4* tp =
            (const float4*)(table + ((size_t)l * TABLE_PAD + idx) * 8);
        float4 t0 = tp[0], t1 = tp[1];
        acc[0] += wgt * t0.x; acc[1] += wgt * t0.y;
        acc[2] += wgt * t0.z; acc[3] += wgt * t0.w;
        acc[4] += wgt * t1.x; acc[5] += wgt * t1.y;
        acc[6] += wgt * t1.z; acc[7] += wgt * t1.w;
      }
    }
    union { unsigned short s[8]; short8 v; } u;
    for (int j = 0; j < 8; ++j) u.s[j] = f2bf(acc[j]);
    int pos = (l ^ (p & 7)) * 8;        // chunk l, swizzled (8 chunks)
    *(short8*)&bufE[p * ENC_STRIDE + pos] = u.v;
  }

  const int lane  = t & 63;
  const int w     = t >> 6;       // 0..7
  const int l15   = lane & 15;
  const int quad  = lane >> 4;
  const int wbase = w * 32;       // this wave's 32 OUTPUT FEATURES

  // ------- MFMA layer (transposed): D = W^T[32 x K] @ X^T[K x 64] ----------
  // A-frag = weights: lane row n = wbase+ft*16+l15, k = quad*8..+7.
  // B-frag = acts:    lane col m = pt*16+l15,       k = quad*8..+7.
  // D runs along n (feature dim) -> epilogue packs 4 bf16 -> one b64 write
  // per tile, already in the [m][k-contiguous] layout the next layer reads.
  auto run_layer = [&](const unsigned short* inb, int in_stride, int smask,
                       unsigned short* outb, const unsigned short* Wpl,
                       int KB) {
    float4v acc[2][4];   // [ft][pt]
    for (int ft = 0; ft < 2; ++ft)
      for (int pt = 0; pt < 4; ++pt)
        acc[ft][pt] = (float4v){0.f, 0.f, 0.f, 0.f};

    for (int kb = 0; kb < KB; ++kb) {
      short8 wf[2], af[4];
      for (int ft = 0; ft < 2; ++ft) {
        int n = wbase + ft * 16 + l15;
        wf[ft] = *(const short8*)&Wpl[(kb * 256 + n) * 32 + quad * 8];
      }
      int kchunk = kb * 4 + quad;
      for (int pt = 0; pt < 4; ++pt) {
        int m = pt * 16 + l15;
        int pos = (kchunk ^ (m & smask)) * 8;
        af[pt] = *(const short8*)&inb[m * in_stride + pos];
      }
      for (int ft = 0; ft < 2; ++ft)
        for (int pt = 0; pt < 4; ++pt)
          acc[ft][pt] = __builtin_amdgcn_mfma_f32_16x16x32_bf16(
              wf[ft], af[pt], acc[ft][pt], 0, 0, 0);
    }

    // Epilogue: ReLU + bf16 pack, one 8 B write per tile.
    // D tile (ft,pt): lane holds rows n0..n0+3 (n0 = wbase+ft*16+quad*4) of
    // col m = pt*16+l15 -> 4 consecutive k-dim shorts in act layout.
    for (int ft = 0; ft < 2; ++ft) {
      int n0 = wbase + ft * 16 + quad * 4;
      int chunk = n0 >> 3, within = n0 & 7;       // within in {0,4}
      for (int pt = 0; pt < 4; ++pt) {
        int m = pt * 16 + l15;
        uint2 pk;
        pk.x = pack2bf(acc[ft][pt][0], acc[ft][pt][1]);
        pk.y = pack2bf(acc[ft][pt][2], acc[ft][pt][3]);
        int pos = (chunk ^ (m & 15)) * 8 + within;
        *(uint2*)&outb[m * ACT_STRIDE + pos] = pk;
      }
    }
  };

  __syncthreads();
  run_layer(bufE, ENC_STRIDE, 7,  bufA, Wp,         2);  // layer 0
  __syncthreads();
  run_layer(bufA, ACT_STRIDE, 15, bufB, Wp + 16384, 8);  // layer 1
  __syncthreads();
  run_layer(bufB, ACT_STRIDE, 15, bufA, Wp + 81920, 8);  // layer 2
  __syncthreads();

  // ---------------- Final layer: out[p] = h2[p] . W3 -----------------------
  {
    int p = t >> 3;          // point within tile (0..63)
    int q = t & 7;           // eighth of K=256 (4 chunks of 8)
    float s = 0.f;
    for (int c8 = 0; c8 < 4; ++c8) {
      int chunk = q * 4 + c8;
      int pos = (chunk ^ (p & 15)) * 8;
      short8 h = *(const short8*)&bufA[p * ACT_STRIDE + pos];
      float4 w0v = *(const float4*)(W3 + chunk * 8);
      float4 w1v = *(const float4*)(W3 + chunk * 8 + 4);
      s += bf2f((unsigned short)h[0]) * w0v.x;
      s += bf2f((unsigned short)h[1]) * w0v.y;
      s += bf2f((unsigned short)h[2]) * w0v.z;
      s += bf2f((unsigned short)h[3]) * w0v.w;
      s += bf2f((unsigned short)h[4]) * w1v.x;
      s += bf2f((unsigned short)h[5]) * w1v.y;
      s += bf2f((unsigned short)h[6]) * w1v.z;
      s += bf2f((unsigned short)h[7]) * w1v.w;
    }
    s += __shfl_xor(s, 1);
    s += __shfl_xor(s, 2);
    s += __shfl_xor(s, 4);
    if (q == 0) out[g0 + p] = s;
  }
}

extern "C" void kernel_launch(void* const* d_in, const int* in_sizes, int n_in,
                              void* d_out, int out_size, void* d_ws,
                              size_t ws_size, hipStream_t stream) {
  const float* x     = (const float*)d_in[0];
  const float* table = (const float*)d_in[1];
  const float* W0    = (const float*)d_in[2];
  const float* W1    = (const float*)d_in[3];
  const float* W2    = (const float*)d_in[4];
  const float* W3    = (const float*)d_in[5];
  float* out = (float*)d_out;
  int N = in_sizes[0] / 2;

  unsigned short* Wp = (unsigned short*)d_ws;   // 147456 bf16 = 288 KB

  // Level params, double precision to match the Python reference exactly.
  LevelParams P;
  const double c = 1.2599210739135742;
  double m = 1.0;
  for (int l = 0; l < N_LEVELS; ++l) {
    double scale_d = 16.0 * m - 1.0;
    int res = (int)std::ceil(scale_d) + 1;
    long long sz = ((long long)res * res + 7) / 8 * 8;
    if (sz > (1LL << 19)) sz = 1LL << 19;
    P.scale[l] = (float)scale_d;
    P.res[l]   = res;
    P.size[l]  = (int)sz;
    m *= c;
  }

  hipLaunchKernelGGL(pack_weights_kernel, dim3(576), dim3(256), 0, stream,
                     W0, W1, W2, Wp);
  hipLaunchKernelGGL(neural_field_kernel, dim3(N / TILE_M), dim3(512), 0,
                     stream, x, table, Wp, W3, out, P);
}

// Round 9
// 190.003 us; speedup vs baseline: 1.3834x; 1.0073x over previous
//
#include <hip/hip_runtime.h>
#include <cmath>

// ---------------------------------------------------------------------------
// NeuralField: hashgrid encode (8 levels x 8 feats, smoothstep) + MLP
// 64 -> 256 -> 256 -> 256 -> 1 (ReLU x3, linear out), N = 262144 points.
// R9: kill addressing VALU. R8 counters: VALUBusy 37% > MfmaUtil 22% - the
// XOR-swizzle address recompute (~25 VALU/K-iter) out-costs the MFMAs.
// Replace XOR swizzle with ADDITIVE padding (ACT stride 264 shorts = 528 B,
// 528 mod 128 = 16 -> b128 lanes spread across banks; ENC stride 72) so the
// per-kb ds_read delta is a constant +64 B -> folds into offset: immediates
// (zero per-iter VALU). Base pointers hoisted out of the K-loop. Tiling,
// 512-thread/8-wave/32-feature structure, (512,4) cap all unchanged (R8:
// no spill at VGPR 52). LDS 75 KB -> still 2 blocks/CU (150 <= 160 KB).
// Spill tripwire: FETCH/WRITE >> 5 MB.
// ---------------------------------------------------------------------------

#define N_LEVELS 8
#define TABLE_PAD 8192
#define TILE_M 64
#define ACT_STRIDE 264       // shorts per activation row (528 B; %128 = 16)
#define ENC_STRIDE 72        // shorts per encode row     (144 B; %128 = 16)

typedef __attribute__((ext_vector_type(8))) short short8;
typedef __attribute__((ext_vector_type(4))) float float4v;

struct LevelParams {
  float scale[N_LEVELS];
  int   res[N_LEVELS];
  int   size[N_LEVELS];
};

__device__ __forceinline__ unsigned short f2bf(float f) {
  unsigned int u = __float_as_uint(f);
  u += 0x7fffu + ((u >> 16) & 1u);      // round to nearest even
  return (unsigned short)(u >> 16);
}
__device__ __forceinline__ float bf2f(unsigned short h) {
  return __uint_as_float(((unsigned int)h) << 16);
}
__device__ __forceinline__ unsigned int pack2bf(float a, float b) {
  a = a > 0.f ? a : 0.f;
  b = b > 0.f ? b : 0.f;
  return (unsigned int)f2bf(a) | ((unsigned int)f2bf(b) << 16);
}

// Pack W (K x 256 row-major f32) -> bf16 [kb][n][ki]: one lane's 16 B A-frag
// (output-feature n, k-chunk) is contiguous; a wave's 16 n x 32 k tile is a
// coalesced 1 KB chunk. Wp layout: [W0p: 2*256*32][W1p+W2p: 8*256*32 each]
__global__ void pack_weights_kernel(const float* __restrict__ W0,
                                    const float* __restrict__ W1,
                                    const float* __restrict__ W2,
                                    unsigned short* __restrict__ Wp) {
  int tid = blockIdx.x * blockDim.x + threadIdx.x;
  const float* src;
  int base, e;
  if (tid < 16384)        { src = W0; base = 0;     e = tid;         }
  else if (tid < 81920)   { src = W1; base = 16384; e = tid - 16384; }
  else if (tid < 147456)  { src = W2; base = 81920; e = tid - 81920; }
  else return;
  int ki = e & 31;
  int n  = (e >> 5) & 255;
  int kb = e >> 13;
  Wp[base + e] = f2bf(src[(kb * 32 + ki) * 256 + n]);
}

__global__ __launch_bounds__(512, 4) void neural_field_kernel(
    const float* __restrict__ x,
    const float* __restrict__ table,
    const unsigned short* __restrict__ Wp,
    const float* __restrict__ W3,
    float* __restrict__ out,
    LevelParams P) {
  // Plain padded layouts, data stored [point m][feature k]:
  //   enc: (m, k) -> m*72  + k      act: (m, k) -> m*264 + k
  __shared__ unsigned short bufE[TILE_M * ENC_STRIDE];   //  9 KB
  __shared__ unsigned short bufA[TILE_M * ACT_STRIDE];   // 33 KB
  __shared__ unsigned short bufB[TILE_M * ACT_STRIDE];   // 33 KB

  const int t  = threadIdx.x;
  const int g0 = blockIdx.x * TILE_M;

  // ------------- Phase 1: hashgrid encode, 1 level/thread -> bufE ----------
  {
    int p = t & 63;        // point within tile
    int l = t >> 6;        // level 0..7
    float2 xy = ((const float2*)x)[g0 + p];
    float scale = P.scale[l];
    int res = P.res[l], size = P.size[l];
    float posx = xy.x * scale + 0.5f;
    float posy = xy.y * scale + 0.5f;
    float pgx = floorf(posx), pgy = floorf(posy);
    float fx = posx - pgx, fy = posy - pgy;
    float wx = fx * fx * (3.0f - 2.0f * fx);
    float wy = fy * fy * (3.0f - 2.0f * fy);
    int px = (int)pgx, py = (int)pgy;
    float acc[8] = {0, 0, 0, 0, 0, 0, 0, 0};
    for (int dy = 0; dy < 2; ++dy) {
      float wyv = dy ? wy : 1.0f - wy;
      for (int dx = 0; dx < 2; ++dx) {
        float wgt = (dx ? wx : 1.0f - wx) * wyv;
        int idx = (px + dx) + (py + dy) * res;
        if (idx >= size) idx -= size;   // idx < 2*size always
        const float4* tp =
            (const float4*)(table + ((size_t)l * TABLE_PAD + idx) * 8);
        float4 t0 = tp[0], t1 = tp[1];
        acc[0] += wgt * t0.x; acc[1] += wgt * t0.y;
        acc[2] += wgt * t0.z; acc[3] += wgt * t0.w;
        acc[4] += wgt * t1.x; acc[5] += wgt * t1.y;
        acc[6] += wgt * t1.z; acc[7] += wgt * t1.w;
      }
    }
    union { unsigned short s[8]; short8 v; } u;
    for (int j = 0; j < 8; ++j) u.s[j] = f2bf(acc[j]);
    *(short8*)&bufE[p * ENC_STRIDE + l * 8] = u.v;
  }

  const int lane  = t & 63;
  const int w     = t >> 6;       // 0..7
  const int l15   = lane & 15;
  const int quad  = lane >> 4;
  const int wbase = w * 32;       // this wave's 32 OUTPUT FEATURES

  // ------- MFMA layer (transposed): D = W^T[32 x K] @ X^T[K x 64] ----------
  // A-frag = weights: lane row n = wbase+ft*16+l15, k = quad*8..+7.
  // B-frag = acts:    lane col m = pt*16+l15,       k = quad*8..+7.
  // Per-kb af delta = +32 shorts (64 B) -> ds_read offset: immediates after
  // unroll; wf delta = +8192 shorts -> scalar pointer bump.
  auto run_layer = [&](const unsigned short* inb, int in_stride,
                       unsigned short* outb, const unsigned short* Wpl,
                       int KB) {
    float4v acc[2][4];   // [ft][pt]
    for (int ft = 0; ft < 2; ++ft)
      for (int pt = 0; pt < 4; ++pt)
        acc[ft][pt] = (float4v){0.f, 0.f, 0.f, 0.f};

    // Hoisted base pointers (per-lane, loop-invariant).
    const unsigned short* ap[4];
    for (int pt = 0; pt < 4; ++pt)
      ap[pt] = &inb[(pt * 16 + l15) * in_stride + quad * 8];
    const unsigned short* wp = &Wpl[(wbase + l15) * 32 + quad * 8];

#pragma unroll
    for (int kb = 0; kb < KB; ++kb) {
      short8 wf[2], af[4];
      for (int ft = 0; ft < 2; ++ft)
        wf[ft] = *(const short8*)(wp + kb * 8192 + ft * 512);
      for (int pt = 0; pt < 4; ++pt)
        af[pt] = *(const short8*)(ap[pt] + kb * 32);
      for (int ft = 0; ft < 2; ++ft)
        for (int pt = 0; pt < 4; ++pt)
          acc[ft][pt] = __builtin_amdgcn_mfma_f32_16x16x32_bf16(
              wf[ft], af[pt], acc[ft][pt], 0, 0, 0);
    }

    // Epilogue: ReLU + bf16 pack, one 8 B write per tile.
    // D tile (ft,pt): lane holds rows n0..n0+3 (n0 = wbase+ft*16+quad*4) of
    // col m = pt*16+l15 -> 4 consecutive k-dim shorts in act layout.
    for (int ft = 0; ft < 2; ++ft) {
      int n0 = wbase + ft * 16 + quad * 4;
      for (int pt = 0; pt < 4; ++pt) {
        int m = pt * 16 + l15;
        uint2 pk;
        pk.x = pack2bf(acc[ft][pt][0], acc[ft][pt][1]);
        pk.y = pack2bf(acc[ft][pt][2], acc[ft][pt][3]);
        *(uint2*)&outb[m * ACT_STRIDE + n0] = pk;
      }
    }
  };

  __syncthreads();
  run_layer(bufE, ENC_STRIDE, bufA, Wp,         2);  // layer 0
  __syncthreads();
  run_layer(bufA, ACT_STRIDE, bufB, Wp + 16384, 8);  // layer 1
  __syncthreads();
  run_layer(bufB, ACT_STRIDE, bufA, Wp + 81920, 8);  // layer 2
  __syncthreads();

  // ---------------- Final layer: out[p] = h2[p] . W3 -----------------------
  {
    int p = t >> 3;          // point within tile (0..63)
    int q = t & 7;           // eighth of K=256 (4 chunks of 8)
    float s = 0.f;
    for (int c8 = 0; c8 < 4; ++c8) {
      int chunk = q * 4 + c8;
      short8 h = *(const short8*)&bufA[p * ACT_STRIDE + chunk * 8];
      float4 w0v = *(const float4*)(W3 + chunk * 8);
      float4 w1v = *(const float4*)(W3 + chunk * 8 + 4);
      s += bf2f((unsigned short)h[0]) * w0v.x;
      s += bf2f((unsigned short)h[1]) * w0v.y;
      s += bf2f((unsigned short)h[2]) * w0v.z;
      s += bf2f((unsigned short)h[3]) * w0v.w;
      s += bf2f((unsigned short)h[4]) * w1v.x;
      s += bf2f((unsigned short)h[5]) * w1v.y;
      s += bf2f((unsigned short)h[6]) * w1v.z;
      s += bf2f((unsigned short)h[7]) * w1v.w;
    }
    s += __shfl_xor(s, 1);
    s += __shfl_xor(s, 2);
    s += __shfl_xor(s, 4);
    if (q == 0) out[g0 + p] = s;
  }
}

extern "C" void kernel_launch(void* const* d_in, const int* in_sizes, int n_in,
                              void* d_out, int out_size, void* d_ws,
                              size_t ws_size, hipStream_t stream) {
  const float* x     = (const float*)d_in[0];
  const float* table = (const float*)d_in[1];
  const float* W0    = (const float*)d_in[2];
  const float* W1    = (const float*)d_in[3];
  const float* W2    = (const float*)d_in[4];
  const float* W3    = (const float*)d_in[5];
  float* out = (float*)d_out;
  int N = in_sizes[0] / 2;

  unsigned short* Wp = (unsigned short*)d_ws;   // 147456 bf16 = 288 KB

  // Level params, double precision to match the Python reference exactly.
  LevelParams P;
  const double c = 1.2599210739135742;
  double m = 1.0;
  for (int l = 0; l < N_LEVELS; ++l) {
    double scale_d = 16.0 * m - 1.0;
    int res = (int)std::ceil(scale_d) + 1;
    long long sz = ((long long)res * res + 7) / 8 * 8;
    if (sz > (1LL << 19)) sz = 1LL << 19;
    P.scale[l] = (float)scale_d;
    P.res[l]   = res;
    P.size[l]  = (int)sz;
    m *= c;
  }

  hipLaunchKernelGGL(pack_weights_kernel, dim3(576), dim3(256), 0, stream,
                     W0, W1, W2, Wp);
  hipLaunchKernelGGL(neural_field_kernel, dim3(N / TILE_M), dim3(512), 0,
                     stream, x, table, Wp, W3, out, P);
}

// Round 10
// 185.279 us; speedup vs baseline: 1.4187x; 1.0255x over previous
//
#include <hip/hip_runtime.h>
#include <cmath>

// ---------------------------------------------------------------------------
// NeuralField: hashgrid encode (8 levels x 8 feats, smoothstep) + MLP
// 64 -> 256 -> 256 -> 256 -> 1 (ReLU x3, linear out), N = 262144 points.
// R10: software-pipelined K-loop. R9 evidence: VGPR=52 (compiler holds ~1
// iter of fragments), all pipes <40% -> latency-bound on wf L2 (~200cy) and
// af LDS (~120cy) round-trips. Explicit 2-stage pipeline: prefetch iter
// k+1's wf+af before iter k's MFMA bundle (spends idle regs on in-flight
// data); each layer's first wf loads issued BEFORE the inter-layer barrier
// (wf depends only on Wp, not LDS) to overlap L2 latency with epilogue +
// barrier drain. Structure otherwise = R9 (512 thr, 8 waves x 32 feats,
// padded strides, (512,4)). Spill tripwire: FETCH/WRITE >> 5 MB.
// ---------------------------------------------------------------------------

#define N_LEVELS 8
#define TABLE_PAD 8192
#define TILE_M 64
#define ACT_STRIDE 264       // shorts per activation row (528 B; %128 = 16)
#define ENC_STRIDE 72        // shorts per encode row     (144 B; %128 = 16)

typedef __attribute__((ext_vector_type(8))) short short8;
typedef __attribute__((ext_vector_type(4))) float float4v;

struct LevelParams {
  float scale[N_LEVELS];
  int   res[N_LEVELS];
  int   size[N_LEVELS];
};

__device__ __forceinline__ unsigned short f2bf(float f) {
  unsigned int u = __float_as_uint(f);
  u += 0x7fffu + ((u >> 16) & 1u);      // round to nearest even
  return (unsigned short)(u >> 16);
}
__device__ __forceinline__ float bf2f(unsigned short h) {
  return __uint_as_float(((unsigned int)h) << 16);
}
__device__ __forceinline__ unsigned int pack2bf(float a, float b) {
  a = a > 0.f ? a : 0.f;
  b = b > 0.f ? b : 0.f;
  return (unsigned int)f2bf(a) | ((unsigned int)f2bf(b) << 16);
}

// Pack W (K x 256 row-major f32) -> bf16 [kb][n][ki]: one lane's 16 B A-frag
// (output-feature n, k-chunk) is contiguous; a wave's 16 n x 32 k tile is a
// coalesced 1 KB chunk. Wp layout: [W0p: 2*256*32][W1p+W2p: 8*256*32 each]
__global__ void pack_weights_kernel(const float* __restrict__ W0,
                                    const float* __restrict__ W1,
                                    const float* __restrict__ W2,
                                    unsigned short* __restrict__ Wp) {
  int tid = blockIdx.x * blockDim.x + threadIdx.x;
  const float* src;
  int base, e;
  if (tid < 16384)        { src = W0; base = 0;     e = tid;         }
  else if (tid < 81920)   { src = W1; base = 16384; e = tid - 16384; }
  else if (tid < 147456)  { src = W2; base = 81920; e = tid - 81920; }
  else return;
  int ki = e & 31;
  int n  = (e >> 5) & 255;
  int kb = e >> 13;
  Wp[base + e] = f2bf(src[(kb * 32 + ki) * 256 + n]);
}

__global__ __launch_bounds__(512, 4) void neural_field_kernel(
    const float* __restrict__ x,
    const float* __restrict__ table,
    const unsigned short* __restrict__ Wp,
    const float* __restrict__ W3,
    float* __restrict__ out,
    LevelParams P) {
  // Plain padded layouts, data stored [point m][feature k]:
  //   enc: (m, k) -> m*72  + k      act: (m, k) -> m*264 + k
  __shared__ unsigned short bufE[TILE_M * ENC_STRIDE];   //  9 KB
  __shared__ unsigned short bufA[TILE_M * ACT_STRIDE];   // 33 KB
  __shared__ unsigned short bufB[TILE_M * ACT_STRIDE];   // 33 KB

  const int t  = threadIdx.x;
  const int g0 = blockIdx.x * TILE_M;

  const int lane  = t & 63;
  const int w     = t >> 6;       // 0..7
  const int l15   = lane & 15;
  const int quad  = lane >> 4;
  const int wbase = w * 32;       // this wave's 32 OUTPUT FEATURES

  // Per-wave weight fragment base offset (element index into a layer's Wp).
  const int woff = (wbase + l15) * 32 + quad * 8;

  // ------------- Phase 1: hashgrid encode, 1 level/thread -> bufE ----------
  {
    int p = t & 63;        // point within tile
    int l = t >> 6;        // level 0..7
    float2 xy = ((const float2*)x)[g0 + p];
    float scale = P.scale[l];
    int res = P.res[l], size = P.size[l];
    float posx = xy.x * scale + 0.5f;
    float posy = xy.y * scale + 0.5f;
    float pgx = floorf(posx), pgy = floorf(posy);
    float fx = posx - pgx, fy = posy - pgy;
    float wx = fx * fx * (3.0f - 2.0f * fx);
    float wy = fy * fy * (3.0f - 2.0f * fy);
    int px = (int)pgx, py = (int)pgy;
    float acc[8] = {0, 0, 0, 0, 0, 0, 0, 0};
    for (int dy = 0; dy < 2; ++dy) {
      float wyv = dy ? wy : 1.0f - wy;
      for (int dx = 0; dx < 2; ++dx) {
        float wgt = (dx ? wx : 1.0f - wx) * wyv;
        int idx = (px + dx) + (py + dy) * res;
        if (idx >= size) idx -= size;   // idx < 2*size always
        const float4* tp =
            (const float4*)(table + ((size_t)l * TABLE_PAD + idx) * 8);
        float4 t0 = tp[0], t1 = tp[1];
        acc[0] += wgt * t0.x; acc[1] += wgt * t0.y;
        acc[2] += wgt * t0.z; acc[3] += wgt * t0.w;
        acc[4] += wgt * t1.x; acc[5] += wgt * t1.y;
        acc[6] += wgt * t1.z; acc[7] += wgt * t1.w;
      }
    }
    union { unsigned short s[8]; short8 v; } u;
    for (int j = 0; j < 8; ++j) u.s[j] = f2bf(acc[j]);
    *(short8*)&bufE[p * ENC_STRIDE + l * 8] = u.v;
  }

  // Preload layer 0's kb=0 weight fragments (no LDS dependency).
  auto preload_w = [&](const unsigned short* Wpl, short8 wf[2]) {
    wf[0] = *(const short8*)(Wpl + woff);
    wf[1] = *(const short8*)(Wpl + woff + 512);
  };

  // ------- MFMA layer (transposed): D = W^T[32 x K] @ X^T[K x 64] ----------
  // 2-stage software pipeline: iter kb's MFMAs overlap iter kb+1's loads.
  // wf0 holds kb=0 fragments, preloaded BEFORE the preceding barrier.
  auto run_layer = [&](const unsigned short* inb, int in_stride,
                       unsigned short* outb, const unsigned short* Wpl,
                       int KB, short8 wf0[2]) {
    float4v acc[2][4];   // [ft][pt]
    for (int ft = 0; ft < 2; ++ft)
      for (int pt = 0; pt < 4; ++pt)
        acc[ft][pt] = (float4v){0.f, 0.f, 0.f, 0.f};

    const unsigned short* ap[4];
    for (int pt = 0; pt < 4; ++pt)
      ap[pt] = &inb[(pt * 16 + l15) * in_stride + quad * 8];
    const unsigned short* wp = Wpl + woff;

    short8 af0[4];
    for (int pt = 0; pt < 4; ++pt)
      af0[pt] = *(const short8*)(ap[pt]);

#pragma unroll
    for (int kb = 0; kb < KB; ++kb) {
      short8 wf1[2], af1[4];
      int kn = (kb + 1 < KB) ? kb + 1 : kb;
      wf1[0] = *(const short8*)(wp + kn * 8192);
      wf1[1] = *(const short8*)(wp + kn * 8192 + 512);
      for (int pt = 0; pt < 4; ++pt)
        af1[pt] = *(const short8*)(ap[pt] + kn * 32);

      for (int ft = 0; ft < 2; ++ft)
        for (int pt = 0; pt < 4; ++pt)
          acc[ft][pt] = __builtin_amdgcn_mfma_f32_16x16x32_bf16(
              wf0[ft], af0[pt], acc[ft][pt], 0, 0, 0);

      wf0[0] = wf1[0]; wf0[1] = wf1[1];
      for (int pt = 0; pt < 4; ++pt) af0[pt] = af1[pt];
    }

    // Epilogue: ReLU + bf16 pack, one 8 B write per tile.
    // D tile (ft,pt): lane holds rows n0..n0+3 (n0 = wbase+ft*16+quad*4) of
    // col m = pt*16+l15 -> 4 consecutive k-dim shorts in act layout.
    for (int ft = 0; ft < 2; ++ft) {
      int n0 = wbase + ft * 16 + quad * 4;
      for (int pt = 0; pt < 4; ++pt) {
        int m = pt * 16 + l15;
        uint2 pk;
        pk.x = pack2bf(acc[ft][pt][0], acc[ft][pt][1]);
        pk.y = pack2bf(acc[ft][pt][2], acc[ft][pt][3]);
        *(uint2*)&outb[m * ACT_STRIDE + n0] = pk;
      }
    }
  };

  short8 wf0[2];
  preload_w(Wp, wf0);                    // L0 kb=0 wf in flight across barrier
  __syncthreads();
  run_layer(bufE, ENC_STRIDE, bufA, Wp,         2, wf0);  // layer 0
  preload_w(Wp + 16384, wf0);            // L1 kb=0 wf overlaps epi + barrier
  __syncthreads();
  run_layer(bufA, ACT_STRIDE, bufB, Wp + 16384, 8, wf0);  // layer 1
  preload_w(Wp + 81920, wf0);            // L2 kb=0 wf overlaps epi + barrier
  __syncthreads();
  run_layer(bufB, ACT_STRIDE, bufA, Wp + 81920, 8, wf0);  // layer 2
  __syncthreads();

  // ---------------- Final layer: out[p] = h2[p] . W3 -----------------------
  {
    int p = t >> 3;          // point within tile (0..63)
    int q = t & 7;           // eighth of K=256 (4 chunks of 8)
    float s = 0.f;
    for (int c8 = 0; c8 < 4; ++c8) {
      int chunk = q * 4 + c8;
      short8 h = *(const short8*)&bufA[p * ACT_STRIDE + chunk * 8];
      float4 w0v = *(const float4*)(W3 + chunk * 8);
      float4 w1v = *(const float4*)(W3 + chunk * 8 + 4);
      s += bf2f((unsigned short)h[0]) * w0v.x;
      s += bf2f((unsigned short)h[1]) * w0v.y;
      s += bf2f((unsigned short)h[2]) * w0v.z;
      s += bf2f((unsigned short)h[3]) * w0v.w;
      s += bf2f((unsigned short)h[4]) * w1v.x;
      s += bf2f((unsigned short)h[5]) * w1v.y;
      s += bf2f((unsigned short)h[6]) * w1v.z;
      s += bf2f((unsigned short)h[7]) * w1v.w;
    }
    s += __shfl_xor(s, 1);
    s += __shfl_xor(s, 2);
    s += __shfl_xor(s, 4);
    if (q == 0) out[g0 + p] = s;
  }
}

extern "C" void kernel_launch(void* const* d_in, const int* in_sizes, int n_in,
                              void* d_out, int out_size, void* d_ws,
                              size_t ws_size, hipStream_t stream) {
  const float* x     = (const float*)d_in[0];
  const float* table = (const float*)d_in[1];
  const float* W0    = (const float*)d_in[2];
  const float* W1    = (const float*)d_in[3];
  const float* W2    = (const float*)d_in[4];
  const float* W3    = (const float*)d_in[5];
  float* out = (float*)d_out;
  int N = in_sizes[0] / 2;

  unsigned short* Wp = (unsigned short*)d_ws;   // 147456 bf16 = 288 KB

  // Level params, double precision to match the Python reference exactly.
  LevelParams P;
  const double c = 1.2599210739135742;
  double m = 1.0;
  for (int l = 0; l < N_LEVELS; ++l) {
    double scale_d = 16.0 * m - 1.0;
    int res = (int)std::ceil(scale_d) + 1;
    long long sz = ((long long)res * res + 7) / 8 * 8;
    if (sz > (1LL << 19)) sz = 1LL << 19;
    P.scale[l] = (float)scale_d;
    P.res[l]   = res;
    P.size[l]  = (int)sz;
    m *= c;
  }

  hipLaunchKernelGGL(pack_weights_kernel, dim3(576), dim3(256), 0, stream,
                     W0, W1, W2, Wp);
  hipLaunchKernelGGL(neural_field_kernel, dim3(N / TILE_M), dim3(512), 0,
                     stream, x, table, Wp, W3, out, P);
}

// Round 11
// 163.695 us; speedup vs baseline: 1.6057x; 1.1319x over previous
//
#include <hip/hip_runtime.h>
#include <cmath>

// ---------------------------------------------------------------------------
// NeuralField: hashgrid encode (8 levels x 8 feats, smoothstep) + MLP
// 64 -> 256 -> 256 -> 256 -> 1 (ReLU x3, linear out), N = 262144 points.
// R11: (a) 32x32x16 MFMA (2495 vs 2075 TF ceiling, HALF the MFMA insts;
// C/D layout verified m74/m101: col=lane&31, row=(reg&3)+8*(reg>>2)+
// 4*(lane>>5)); (b) final 256->1 layer FUSED into layer 2's accumulators:
// relu+dot with W3 straight from fp32 acc regs, shfl_xor(32) + 2.3 KB LDS
// cross-wave reduce. Kills layer-2 pack/writes, the 32 KB h2 round-trip,
// and the separate final-dot phase. TLP is hard-capped at 4 waves/SIMD
// (m69 power-of-2 reg quantum; this tile needs >64 regs), so this round
// reduces WORK per wave instead. Weight pack layout now [k/16][n][k%16].
// Spill tripwire: FETCH/WRITE >> 5 MB.
// ---------------------------------------------------------------------------

#define N_LEVELS 8
#define TABLE_PAD 8192
#define TILE_M 64
#define ACT_STRIDE 264       // shorts per activation row
#define ENC_STRIDE 72        // shorts per encode row

typedef __attribute__((ext_vector_type(8))) short short8;
typedef __attribute__((ext_vector_type(16))) float float16v;

struct LevelParams {
  float scale[N_LEVELS];
  int   res[N_LEVELS];
  int   size[N_LEVELS];
};

__device__ __forceinline__ unsigned short f2bf(float f) {
  unsigned int u = __float_as_uint(f);
  u += 0x7fffu + ((u >> 16) & 1u);      // round to nearest even
  return (unsigned short)(u >> 16);
}
__device__ __forceinline__ unsigned int pack2bf(float a, float b) {
  a = a > 0.f ? a : 0.f;
  b = b > 0.f ? b : 0.f;
  return (unsigned int)f2bf(a) | ((unsigned int)f2bf(b) << 16);
}

// Pack W (K x 256 row-major f32) -> bf16 [k/16][n][k%16]: one lane's 16 B
// A-frag for 32x32x16 (feature n, k-half h8) is contiguous at n*16 + h8*8.
// Wp layout: [W0p: 4*4096][W1p: 16*4096][W2p: 16*4096] shorts.
__global__ void pack_weights_kernel(const float* __restrict__ W0,
                                    const float* __restrict__ W1,
                                    const float* __restrict__ W2,
                                    unsigned short* __restrict__ Wp) {
  int tid = blockIdx.x * blockDim.x + threadIdx.x;
  const float* src;
  int base, e;
  if (tid < 16384)        { src = W0; base = 0;     e = tid;         }
  else if (tid < 81920)   { src = W1; base = 16384; e = tid - 16384; }
  else if (tid < 147456)  { src = W2; base = 81920; e = tid - 81920; }
  else return;
  int ki = e & 15;
  int n  = (e >> 4) & 255;
  int kb = e >> 12;
  unsigned int u = __float_as_uint(src[(kb * 16 + ki) * 256 + n]);
  u += 0x7fffu + ((u >> 16) & 1u);
  Wp[base + e] = (unsigned short)(u >> 16);
}

__global__ __launch_bounds__(512, 4) void neural_field_kernel(
    const float* __restrict__ x,
    const float* __restrict__ table,
    const unsigned short* __restrict__ Wp,
    const float* __restrict__ W3,
    float* __restrict__ out,
    LevelParams P) {
  // Padded layouts, data stored [point m][feature k]:
  //   enc: (m, k) -> m*72 + k      act: (m, k) -> m*264 + k
  __shared__ unsigned short bufE[TILE_M * ENC_STRIDE];   //  9 KB (-> fsum)
  __shared__ unsigned short bufA[TILE_M * ACT_STRIDE];   // 33 KB
  __shared__ unsigned short bufB[TILE_M * ACT_STRIDE];   // 33 KB

  const int t  = threadIdx.x;
  const int g0 = blockIdx.x * TILE_M;

  const int lane  = t & 63;
  const int w     = t >> 6;       // 0..7
  const int l31   = lane & 31;
  const int h8    = lane >> 5;    // 0/1: k-half within a 16-k step
  const int wbase = w * 32;       // this wave's 32 OUTPUT FEATURES

  // Per-wave weight A-frag base offset (elements) in a layer's packed W.
  const int woff = (wbase + l31) * 16 + h8 * 8;

  // ------------- Phase 1: hashgrid encode, 1 level/thread -> bufE ----------
  {
    int p = t & 63;        // point within tile
    int l = t >> 6;        // level 0..7
    float2 xy = ((const float2*)x)[g0 + p];
    float scale = P.scale[l];
    int res = P.res[l], size = P.size[l];
    float posx = xy.x * scale + 0.5f;
    float posy = xy.y * scale + 0.5f;
    float pgx = floorf(posx), pgy = floorf(posy);
    float fx = posx - pgx, fy = posy - pgy;
    float wx = fx * fx * (3.0f - 2.0f * fx);
    float wy = fy * fy * (3.0f - 2.0f * fy);
    int px = (int)pgx, py = (int)pgy;
    float acc[8] = {0, 0, 0, 0, 0, 0, 0, 0};
    for (int dy = 0; dy < 2; ++dy) {
      float wyv = dy ? wy : 1.0f - wy;
      for (int dx = 0; dx < 2; ++dx) {
        float wgt = (dx ? wx : 1.0f - wx) * wyv;
        int idx = (px + dx) + (py + dy) * res;
        if (idx >= size) idx -= size;   // idx < 2*size always
        const float4* tp =
            (const float4*)(table + ((size_t)l * TABLE_PAD + idx) * 8);
        float4 t0 = tp[0], t1 = tp[1];
        acc[0] += wgt * t0.x; acc[1] += wgt * t0.y;
        acc[2] += wgt * t0.z; acc[3] += wgt * t0.w;
        acc[4] += wgt * t1.x; acc[5] += wgt * t1.y;
        acc[6] += wgt * t1.z; acc[7] += wgt * t1.w;
      }
    }
    union { unsigned short s[8]; short8 v; } u;
    for (int j = 0; j < 8; ++j) u.s[j] = f2bf(acc[j]);
    *(short8*)&bufE[p * ENC_STRIDE + l * 8] = u.v;
  }

  // ---- MFMA layer (transposed, 32x32x16): D = W^T[32 x K] @ X^T[K x 64] ---
  // A-frag (weights): row n = wbase+l31, k = s*16 + h8*8 + j.
  // B-frag (acts):    col m = pt*32+l31, k = s*16 + h8*8 + j.
  // D: col m = pt*32+l31; rows: reg 4q+r -> n = wbase + 8q + 4h8 + r.
  // fuse_final: instead of writing h2, dot acc with W3 in registers.
  auto run_layer = [&](const unsigned short* inb, int in_stride,
                       unsigned short* outb, const unsigned short* Wpl,
                       int KB, short8 wf0, bool fuse_final,
                       float* fsum) {
    float16v acc[2];
    for (int j = 0; j < 16; ++j) { acc[0][j] = 0.f; acc[1][j] = 0.f; }

    const unsigned short* ap0 = &inb[l31 * in_stride + h8 * 8];
    const unsigned short* ap1 = ap0 + 32 * in_stride;
    const unsigned short* wp  = Wpl + woff;

    float w3f[16];
    if (fuse_final) {
      for (int q = 0; q < 4; ++q) {
        float4 wv = *(const float4*)(W3 + wbase + 8 * q + 4 * h8);
        w3f[4 * q + 0] = wv.x; w3f[4 * q + 1] = wv.y;
        w3f[4 * q + 2] = wv.z; w3f[4 * q + 3] = wv.w;
      }
    }

    short8 af0[2];
    af0[0] = *(const short8*)(ap0);
    af0[1] = *(const short8*)(ap1);

#pragma unroll
    for (int kb = 0; kb < KB; ++kb) {
      short8 wf1, af1[2];
      int kn = (kb + 1 < KB) ? kb + 1 : kb;
      wf1    = *(const short8*)(wp + kn * 4096);
      af1[0] = *(const short8*)(ap0 + kn * 16);
      af1[1] = *(const short8*)(ap1 + kn * 16);

      acc[0] = __builtin_amdgcn_mfma_f32_32x32x16_bf16(wf0, af0[0], acc[0],
                                                       0, 0, 0);
      acc[1] = __builtin_amdgcn_mfma_f32_32x32x16_bf16(wf0, af0[1], acc[1],
                                                       0, 0, 0);
      wf0 = wf1; af0[0] = af1[0]; af0[1] = af1[1];
    }

    if (!fuse_final) {
      // Epilogue: ReLU + bf16 pack; 4 b64 writes per pt-tile, already in
      // the next layer's [m][k-contiguous] layout.
      for (int pt = 0; pt < 2; ++pt) {
        int m = pt * 32 + l31;
        for (int q = 0; q < 4; ++q) {
          int n0 = wbase + 8 * q + 4 * h8;
          uint2 pk;
          pk.x = pack2bf(acc[pt][4 * q + 0], acc[pt][4 * q + 1]);
          pk.y = pack2bf(acc[pt][4 * q + 2], acc[pt][4 * q + 3]);
          *(uint2*)&outb[m * ACT_STRIDE + n0] = pk;
        }
      }
    } else {
      // Fused final layer: per-lane relu-dot over this wave's 32 features
      // (16 per k-half), combine halves via shfl_xor(32), stage per-wave
      // partials to fsum[m*9 + w] (stride 9 breaks write conflicts).
      float part0 = 0.f, part1 = 0.f;
      for (int j = 0; j < 16; ++j) {
        float v0 = acc[0][j]; v0 = v0 > 0.f ? v0 : 0.f;
        float v1 = acc[1][j]; v1 = v1 > 0.f ? v1 : 0.f;
        part0 += v0 * w3f[j];
        part1 += v1 * w3f[j];
      }
      part0 += __shfl_xor(part0, 32);
      part1 += __shfl_xor(part1, 32);
      float val = h8 ? part1 : part0;   // lane holds m = h8*32 + l31 = lane
      fsum[lane * 9 + w] = val;
    }
  };

  float* fsum = (float*)bufE;           // bufE dead after layer 0

  short8 wf = *(const short8*)(Wp + woff);          // L0 wf preload
  __syncthreads();
  run_layer(bufE, ENC_STRIDE, bufA, Wp, 4, wf, false, fsum);        // layer 0
  wf = *(const short8*)(Wp + 16384 + woff);         // L1 wf preload
  __syncthreads();
  run_layer(bufA, ACT_STRIDE, bufB, Wp + 16384, 16, wf, false, fsum); // lyr 1
  wf = *(const short8*)(Wp + 81920 + woff);         // L2 wf preload
  __syncthreads();
  run_layer(bufB, ACT_STRIDE, nullptr, Wp + 81920, 16, wf, true, fsum); // l2+3
  __syncthreads();

  // ---------------- Cross-wave reduce of fsum -> out -----------------------
  {
    int p = t >> 3;          // point within tile (0..63)
    int q = t & 7;           // wave index being summed
    float v = fsum[p * 9 + q];
    v += __shfl_xor(v, 1);
    v += __shfl_xor(v, 2);
    v += __shfl_xor(v, 4);
    if (q == 0) out[g0 + p] = v;
  }
}

extern "C" void kernel_launch(void* const* d_in, const int* in_sizes, int n_in,
                              void* d_out, int out_size, void* d_ws,
                              size_t ws_size, hipStream_t stream) {
  const float* x     = (const float*)d_in[0];
  const float* table = (const float*)d_in[1];
  const float* W0    = (const float*)d_in[2];
  const float* W1    = (const float*)d_in[3];
  const float* W2    = (const float*)d_in[4];
  const float* W3    = (const float*)d_in[5];
  float* out = (float*)d_out;
  int N = in_sizes[0] / 2;

  unsigned short* Wp = (unsigned short*)d_ws;   // 147456 bf16 = 288 KB

  // Level params, double precision to match the Python reference exactly.
  LevelParams P;
  const double c = 1.2599210739135742;
  double m = 1.0;
  for (int l = 0; l < N_LEVELS; ++l) {
    double scale_d = 16.0 * m - 1.0;
    int res = (int)std::ceil(scale_d) + 1;
    long long sz = ((long long)res * res + 7) / 8 * 8;
    if (sz > (1LL << 19)) sz = 1LL << 19;
    P.scale[l] = (float)scale_d;
    P.res[l]   = res;
    P.size[l]  = (int)sz;
    m *= c;
  }

  hipLaunchKernelGGL(pack_weights_kernel, dim3(576), dim3(256), 0, stream,
                     W0, W1, W2, Wp);
  hipLaunchKernelGGL(neural_field_kernel, dim3(N / TILE_M), dim3(512), 0,
                     stream, x, table, Wp, W3, out, P);
}

// Round 12
// 156.160 us; speedup vs baseline: 1.6832x; 1.0483x over previous
//
#include <hip/hip_runtime.h>
#include <cmath>

// ---------------------------------------------------------------------------
// NeuralField: hashgrid encode (8 levels x 8 feats, smoothstep) + MLP
// 64 -> 256 -> 256 -> 256 -> 1 (ReLU x3, linear out), N = 262144 points.
// R12: occupancy via LDS cut. R11 (109 us, 31% MfmaUtil) runs 52 VGPRs but
// 76.8 KB LDS -> 2 blocks/CU. Replace double-buffer with ONE in-place act
// buffer (mid-layer barrier between last K-loop read and epilogue write;
// mechanism proven R6) -> 42 KB -> 3 blocks/CU, 24 waves/CU (+50% TLP).
// __launch_bounds__(512,6) = 85-reg cap (52 used -> no spill risk).
// Everything else = R11: 32x32x16 MFMA, fused final layer, padded strides.
// Spill tripwire: FETCH/WRITE >> 5 MB.
// ---------------------------------------------------------------------------

#define N_LEVELS 8
#define TABLE_PAD 8192
#define TILE_M 64
#define ACT_STRIDE 264       // shorts per activation row
#define ENC_STRIDE 72        // shorts per encode row

typedef __attribute__((ext_vector_type(8))) short short8;
typedef __attribute__((ext_vector_type(16))) float float16v;

struct LevelParams {
  float scale[N_LEVELS];
  int   res[N_LEVELS];
  int   size[N_LEVELS];
};

__device__ __forceinline__ unsigned short f2bf(float f) {
  unsigned int u = __float_as_uint(f);
  u += 0x7fffu + ((u >> 16) & 1u);      // round to nearest even
  return (unsigned short)(u >> 16);
}
__device__ __forceinline__ unsigned int pack2bf(float a, float b) {
  a = a > 0.f ? a : 0.f;
  b = b > 0.f ? b : 0.f;
  return (unsigned int)f2bf(a) | ((unsigned int)f2bf(b) << 16);
}

// Pack W (K x 256 row-major f32) -> bf16 [k/16][n][k%16]: one lane's 16 B
// A-frag for 32x32x16 (feature n, k-half h8) is contiguous at n*16 + h8*8.
// Wp layout: [W0p: 4*4096][W1p: 16*4096][W2p: 16*4096] shorts.
__global__ void pack_weights_kernel(const float* __restrict__ W0,
                                    const float* __restrict__ W1,
                                    const float* __restrict__ W2,
                                    unsigned short* __restrict__ Wp) {
  int tid = blockIdx.x * blockDim.x + threadIdx.x;
  const float* src;
  int base, e;
  if (tid < 16384)        { src = W0; base = 0;     e = tid;         }
  else if (tid < 81920)   { src = W1; base = 16384; e = tid - 16384; }
  else if (tid < 147456)  { src = W2; base = 81920; e = tid - 81920; }
  else return;
  int ki = e & 15;
  int n  = (e >> 4) & 255;
  int kb = e >> 12;
  unsigned int u = __float_as_uint(src[(kb * 16 + ki) * 256 + n]);
  u += 0x7fffu + ((u >> 16) & 1u);
  Wp[base + e] = (unsigned short)(u >> 16);
}

__global__ __launch_bounds__(512, 6) void neural_field_kernel(
    const float* __restrict__ x,
    const float* __restrict__ table,
    const unsigned short* __restrict__ Wp,
    const float* __restrict__ W3,
    float* __restrict__ out,
    LevelParams P) {
  // Padded layouts, data stored [point m][feature k]:
  //   enc: (m, k) -> m*72 + k      act: (m, k) -> m*264 + k
  __shared__ unsigned short bufE[TILE_M * ENC_STRIDE];   //  9 KB (-> fsum)
  __shared__ unsigned short bufA[TILE_M * ACT_STRIDE];   // 33 KB, in-place

  const int t  = threadIdx.x;
  const int g0 = blockIdx.x * TILE_M;

  const int lane  = t & 63;
  const int w     = t >> 6;       // 0..7
  const int l31   = lane & 31;
  const int h8    = lane >> 5;    // 0/1: k-half within a 16-k step
  const int wbase = w * 32;       // this wave's 32 OUTPUT FEATURES

  // Per-wave weight A-frag base offset (elements) in a layer's packed W.
  const int woff = (wbase + l31) * 16 + h8 * 8;

  // ------------- Phase 1: hashgrid encode, 1 level/thread -> bufE ----------
  {
    int p = t & 63;        // point within tile
    int l = t >> 6;        // level 0..7
    float2 xy = ((const float2*)x)[g0 + p];
    float scale = P.scale[l];
    int res = P.res[l], size = P.size[l];
    float posx = xy.x * scale + 0.5f;
    float posy = xy.y * scale + 0.5f;
    float pgx = floorf(posx), pgy = floorf(posy);
    float fx = posx - pgx, fy = posy - pgy;
    float wx = fx * fx * (3.0f - 2.0f * fx);
    float wy = fy * fy * (3.0f - 2.0f * fy);
    int px = (int)pgx, py = (int)pgy;
    float acc[8] = {0, 0, 0, 0, 0, 0, 0, 0};
    for (int dy = 0; dy < 2; ++dy) {
      float wyv = dy ? wy : 1.0f - wy;
      for (int dx = 0; dx < 2; ++dx) {
        float wgt = (dx ? wx : 1.0f - wx) * wyv;
        int idx = (px + dx) + (py + dy) * res;
        if (idx >= size) idx -= size;   // idx < 2*size always
        const float4* tp =
            (const float4*)(table + ((size_t)l * TABLE_PAD + idx) * 8);
        float4 t0 = tp[0], t1 = tp[1];
        acc[0] += wgt * t0.x; acc[1] += wgt * t0.y;
        acc[2] += wgt * t0.z; acc[3] += wgt * t0.w;
        acc[4] += wgt * t1.x; acc[5] += wgt * t1.y;
        acc[6] += wgt * t1.z; acc[7] += wgt * t1.w;
      }
    }
    union { unsigned short s[8]; short8 v; } u;
    for (int j = 0; j < 8; ++j) u.s[j] = f2bf(acc[j]);
    *(short8*)&bufE[p * ENC_STRIDE + l * 8] = u.v;
  }

  // ---- MFMA layer (transposed, 32x32x16): D = W^T[32 x K] @ X^T[K x 64] ---
  // A-frag (weights): row n = wbase+l31, k = s*16 + h8*8 + j.
  // B-frag (acts):    col m = pt*32+l31, k = s*16 + h8*8 + j.
  // D: col m = pt*32+l31; rows: reg 4q+r -> n = wbase + 8q + 4h8 + r.
  // inplace: barrier between last K-loop read and the epilogue overwrite.
  // fuse_final: dot acc with W3 in registers instead of writing h2.
  auto run_layer = [&](const unsigned short* inb, int in_stride,
                       unsigned short* outb, const unsigned short* Wpl,
                       int KB, short8 wf0, bool inplace, bool fuse_final,
                       float* fsum) {
    float16v acc[2];
    for (int j = 0; j < 16; ++j) { acc[0][j] = 0.f; acc[1][j] = 0.f; }

    const unsigned short* ap0 = &inb[l31 * in_stride + h8 * 8];
    const unsigned short* ap1 = ap0 + 32 * in_stride;
    const unsigned short* wp  = Wpl + woff;

    float w3f[16];
    if (fuse_final) {
      for (int q = 0; q < 4; ++q) {
        float4 wv = *(const float4*)(W3 + wbase + 8 * q + 4 * h8);
        w3f[4 * q + 0] = wv.x; w3f[4 * q + 1] = wv.y;
        w3f[4 * q + 2] = wv.z; w3f[4 * q + 3] = wv.w;
      }
    }

    short8 af0[2];
    af0[0] = *(const short8*)(ap0);
    af0[1] = *(const short8*)(ap1);

#pragma unroll
    for (int kb = 0; kb < KB; ++kb) {
      short8 wf1, af1[2];
      int kn = (kb + 1 < KB) ? kb + 1 : kb;
      wf1    = *(const short8*)(wp + kn * 4096);
      af1[0] = *(const short8*)(ap0 + kn * 16);
      af1[1] = *(const short8*)(ap1 + kn * 16);

      acc[0] = __builtin_amdgcn_mfma_f32_32x32x16_bf16(wf0, af0[0], acc[0],
                                                       0, 0, 0);
      acc[1] = __builtin_amdgcn_mfma_f32_32x32x16_bf16(wf0, af0[1], acc[1],
                                                       0, 0, 0);
      wf0 = wf1; af0[0] = af1[0]; af0[1] = af1[1];
    }

    if (inplace) __syncthreads();   // all K-loop reads done before overwrite

    if (!fuse_final) {
      // Epilogue: ReLU + bf16 pack; 4 b64 writes per pt-tile, already in
      // the next layer's [m][k-contiguous] layout.
      for (int pt = 0; pt < 2; ++pt) {
        int m = pt * 32 + l31;
        for (int q = 0; q < 4; ++q) {
          int n0 = wbase + 8 * q + 4 * h8;
          uint2 pk;
          pk.x = pack2bf(acc[pt][4 * q + 0], acc[pt][4 * q + 1]);
          pk.y = pack2bf(acc[pt][4 * q + 2], acc[pt][4 * q + 3]);
          *(uint2*)&outb[m * ACT_STRIDE + n0] = pk;
        }
      }
    } else {
      // Fused final layer: per-lane relu-dot over this wave's 32 features
      // (16 per k-half), combine halves via shfl_xor(32), stage per-wave
      // partials to fsum[m*9 + w] (stride 9 breaks write conflicts).
      float part0 = 0.f, part1 = 0.f;
      for (int j = 0; j < 16; ++j) {
        float v0 = acc[0][j]; v0 = v0 > 0.f ? v0 : 0.f;
        float v1 = acc[1][j]; v1 = v1 > 0.f ? v1 : 0.f;
        part0 += v0 * w3f[j];
        part1 += v1 * w3f[j];
      }
      part0 += __shfl_xor(part0, 32);
      part1 += __shfl_xor(part1, 32);
      float val = h8 ? part1 : part0;   // lane holds m = h8*32 + l31 = lane
      fsum[lane * 9 + w] = val;
    }
  };

  float* fsum = (float*)bufE;           // bufE dead after layer 0

  short8 wf = *(const short8*)(Wp + woff);          // L0 wf preload
  __syncthreads();
  // Layer 0: bufE -> bufA (disjoint buffers, no in-place hazard)
  run_layer(bufE, ENC_STRIDE, bufA, Wp, 4, wf, false, false, fsum);
  wf = *(const short8*)(Wp + 16384 + woff);         // L1 wf preload
  __syncthreads();
  // Layer 1: bufA -> bufA IN-PLACE (mid-layer barrier inside)
  run_layer(bufA, ACT_STRIDE, bufA, Wp + 16384, 16, wf, true, false, fsum);
  wf = *(const short8*)(Wp + 81920 + woff);         // L2 wf preload
  __syncthreads();
  // Layer 2 + final: reads bufA, writes only fsum (bufE region, disjoint)
  run_layer(bufA, ACT_STRIDE, nullptr, Wp + 81920, 16, wf, false, true, fsum);
  __syncthreads();

  // ---------------- Cross-wave reduce of fsum -> out -----------------------
  {
    int p = t >> 3;          // point within tile (0..63)
    int q = t & 7;           // wave index being summed
    float v = fsum[p * 9 + q];
    v += __shfl_xor(v, 1);
    v += __shfl_xor(v, 2);
    v += __shfl_xor(v, 4);
    if (q == 0) out[g0 + p] = v;
  }
}

extern "C" void kernel_launch(void* const* d_in, const int* in_sizes, int n_in,
                              void* d_out, int out_size, void* d_ws,
                              size_t ws_size, hipStream_t stream) {
  const float* x     = (const float*)d_in[0];
  const float* table = (const float*)d_in[1];
  const float* W0    = (const float*)d_in[2];
  const float* W1    = (const float*)d_in[3];
  const float* W2    = (const float*)d_in[4];
  const float* W3    = (const float*)d_in[5];
  float* out = (float*)d_out;
  int N = in_sizes[0] / 2;

  unsigned short* Wp = (unsigned short*)d_ws;   // 147456 bf16 = 288 KB

  // Level params, double precision to match the Python reference exactly.
  LevelParams P;
  const double c = 1.2599210739135742;
  double m = 1.0;
  for (int l = 0; l < N_LEVELS; ++l) {
    double scale_d = 16.0 * m - 1.0;
    int res = (int)std::ceil(scale_d) + 1;
    long long sz = ((long long)res * res + 7) / 8 * 8;
    if (sz > (1LL << 19)) sz = 1LL << 19;
    P.scale[l] = (float)scale_d;
    P.res[l]   = res;
    P.size[l]  = (int)sz;
    m *= c;
  }

  hipLaunchKernelGGL(pack_weights_kernel, dim3(576), dim3(256), 0, stream,
                     W0, W1, W2, Wp);
  hipLaunchKernelGGL(neural_field_kernel, dim3(N / TILE_M), dim3(512), 0,
                     stream, x, table, Wp, W3, out, P);
}